// Round 2
// baseline (292.183 us; speedup 1.0000x reference)
//
#include <hip/hip_runtime.h>
#include <math.h>

#define B 1024
#define T 512
#define S 48
#define SOS 47

// broadcast lane l's value to all lanes via the SGPR file
__device__ __forceinline__ float rdlanef(float v, int l) {
    return __int_as_float(__builtin_amdgcn_readlane(__float_as_int(v), l));
}

// ---------------------------------------------------------------------------
// Fused CRF loss. One wave per row; lane i owns state i; expT row in VGPRs.
// Scan kept in exp space with DELAYED normalization:
//   invariant  u_t = q * exp(M)   (exact; r_s == exp(-l_s) pending factor)
//   live step: q' = (expT q) * exp(emis - er) * r_s ;  M += er + l_s
//              then r_s = rcp(d1), l_s = log(d1)   [off critical chain]
//
// ROUND 2 (this session): HYBRID q-broadcast, half SGPR / half LDS-pipelined.
// Round 1 (all-readlane) is issue-bound: ~106 VALU instrs/step (48 rl +
// 48 fma + overhead) on ONE wave/SIMD with no TLP. Round 0 (all-LDS) was
// latency-bound: 12 ds_read_b128 + ~130cy LDS round trip ON the chain.
// Hybrid takes the best of both:
//   - j=0..23 via 24 v_readlane -> SGPR (consumed FIRST in the fma order)
//   - j=24..47 via 1 ds_write + 6 ds_read_b128, ISSUED AT THE END of step t
//     and CONSUMED MID-STEP t+1: the ~130cy LDS latency hides under the
//     ~150cy of readlanes+first-half fmas that run before the data is
//     needed. DS is in-order per wave, so a single 64-float buffer is
//     hazard-free (step t+1's write follows step t's reads in program
//     order), and same-address reads are conflict-free broadcasts.
// Net: per-step VALU stream ~106 -> ~82 instrs; DS costs 7 issue slots with
// zero exposed latency. Accumulation order is bitwise identical to rounds
// 0/1 (same j->chain assignment and order; only the transport of q_j
// changed, not its bits).
// Emission/mask prefetch double-buffered per 8-step block so vmem waits only
// ever hit loads aged by a full block. amdgpu_waves_per_eu(1): full VGPR
// budget; occupancy is structurally 1 wave/SIMD (1024 single-wave blocks).
// ---------------------------------------------------------------------------
__global__ __launch_bounds__(64, 1)
__attribute__((amdgpu_waves_per_eu(1)))
void crf_fused(const float* __restrict__ feat,
               const int* __restrict__ states,
               const float* __restrict__ mask,
               const float* __restrict__ trans,
               float* __restrict__ out) {
    __shared__ __align__(16) float pbuf[64];
    const int b = blockIdx.x;
    const int lane = threadIdx.x;
    const int elane = (lane < S) ? lane : 0;    // lanes 48-63 shadow lane 0
    const float* f_b = feat + (size_t)b * T * S;
    const float* m_b = mask + b * T;
    const int* st_b = states + b * T;

    // ---- numerator (latency overlaps expT setup) ----
    float nsum = 0.f;
#pragma unroll
    for (int k2 = 0; k2 < T / 64; ++k2) {
        const int t = lane + k2 * 64;
        const int st = st_b[t];
        const int pv = (t == 0) ? SOS : st_b[t - 1];
        nsum += (f_b[t * S + st] + trans[st * S + pv]) * m_b[t];
    }

    // ---- expT row for this lane; exp(-9999) underflows to exact 0 ----
    float expT[S];
    {
        const float4* t4 = (const float4*)(trans + elane * S);
#pragma unroll
        for (int j4 = 0; j4 < S / 4; ++j4) {
            const float4 tv = t4[j4];
            expT[4 * j4 + 0] = (lane < S) ? __expf(tv.x) : 0.f;
            expT[4 * j4 + 1] = (lane < S) ? __expf(tv.y) : 0.f;
            expT[4 * j4 + 2] = (lane < S) ? __expf(tv.z) : 0.f;
            expT[4 * j4 + 3] = (lane < S) ? __expf(tv.w) : 0.f;
        }
    }

    // ---- scan state ----
    float q = (lane == SOS) ? 1.f : 0.f;        // lanes >= 48 hold 0 forever
    float M = 0.f;
    float r_s = 1.f, l_s = 0.f;      // pending normalizer: r_s == exp(-l_s)

    // seed the LDS-pipelined upper-half broadcast (j = 24..47) for step 0
    pbuf[lane] = q;
    const float4* qb = (const float4*)pbuf;
    float4 qh[6];
#pragma unroll
    for (int r = 0; r < 6; ++r) qh[r] = qb[6 + r];   // floats 24..47

    // emission/mask double-buffered block rings (8 steps per block)
    float ering[2][8], mring[2][8];
#pragma unroll
    for (int k = 0; k < 8; ++k) {
        ering[0][k] = f_b[k * S + elane];
        mring[0][k] = m_b[k];
    }

#pragma unroll 2
    for (int tb = 0; tb < T / 8; ++tb) {
        const int pb = tb & 1;
        // issue next block's loads now; consumed a full block later
        const int tn = ((tb + 1) & (T / 8 - 1)) * 8;   // wrap: last refill unused
#pragma unroll
        for (int k = 0; k < 8; ++k) {
            ering[pb ^ 1][k] = f_b[(tn + k) * S + elane];
            mring[pb ^ 1][k] = m_b[tn + k];
        }
#pragma unroll
        for (int k = 0; k < 8; ++k) {
            // off-chain: per-lane factor from prefetched emission
            const float emis = ering[pb][k];
            const float er = rdlanef(emis, 1);
            const float F = __expf(emis - er) * r_s;
            // chain: dot d_i = expT[i] . q
            //   lower half (j=0..23): SGPR broadcast via readlane
            //   upper half (j=24..47): qh[] float4s read from LDS at the END
            //   of the PREVIOUS step (latency fully hidden)
            float ax = 0.f, ay = 0.f, az = 0.f, aw = 0.f;
#pragma unroll
            for (int j4 = 0; j4 < 6; ++j4) {
                ax = fmaf(expT[4 * j4 + 0], rdlanef(q, 4 * j4 + 0), ax);
                ay = fmaf(expT[4 * j4 + 1], rdlanef(q, 4 * j4 + 1), ay);
                az = fmaf(expT[4 * j4 + 2], rdlanef(q, 4 * j4 + 2), az);
                aw = fmaf(expT[4 * j4 + 3], rdlanef(q, 4 * j4 + 3), aw);
            }
#pragma unroll
            for (int r = 0; r < 6; ++r) {
                ax = fmaf(expT[24 + 4 * r + 0], qh[r].x, ax);
                ay = fmaf(expT[24 + 4 * r + 1], qh[r].y, ay);
                az = fmaf(expT[24 + 4 * r + 2], qh[r].z, az);
                aw = fmaf(expT[24 + 4 * r + 3], qh[r].w, aw);
            }
            const float d = (ax + ay) + (az + aw);
            const float qn = d * F;
            const bool live = (mring[pb][k] != 0.f);
            q = live ? qn : q;                  // SELECT, never blend
            // publish q and issue next step's upper-half broadcast reads NOW;
            // they have a full step (~150+ cyc of rl/fma issue) to return.
            // DS is in-order per wave: write -> reads -> (next step's write)
            // never reorders, so the single buffer is safe.
            pbuf[lane] = q;
#pragma unroll
            for (int r = 0; r < 6; ++r) qh[r] = qb[6 + r];
            // off-chain: next normalizer + shift bookkeeping
            M = live ? (M + er + l_s) : M;      // uses OLD l_s, then update
            const float dr = rdlanef(d, 1);     // lane1 dot: provably > 0
            const float nl = __logf(dr);
            const float nr = __builtin_amdgcn_rcpf(dr);
            r_s = live ? nr : r_s;
            l_s = live ? nl : l_s;
        }
    }

    // ---- epilogue: denom = M + log(sum_i q_i); out = denom - numer ----
    float ps = q;                               // lanes >= 48 hold 0
#pragma unroll
    for (int off = 32; off > 0; off >>= 1) {
        ps += __shfl_xor(ps, off, 64);
        nsum += __shfl_xor(nsum, off, 64);
    }
    if (lane == 0) out[b] = M + __logf(ps) - nsum;
}

extern "C" void kernel_launch(void* const* d_in, const int* in_sizes, int n_in,
                              void* d_out, int out_size, void* d_ws, size_t ws_size,
                              hipStream_t stream) {
    const float* feat   = (const float*)d_in[0];   // (B,T,S) f32
    const int*   states = (const int*)d_in[1];     // (B,T) i32
    const float* mask   = (const float*)d_in[2];   // (B,T) f32
    const float* trans  = (const float*)d_in[3];   // (S,S) f32
    float* out = (float*)d_out;                    // (B,) f32

    crf_fused<<<dim3(B), dim3(64), 0, stream>>>(feat, states, mask, trans, out);
}

// Round 3
// 252.865 us; speedup vs baseline: 1.1555x; 1.1555x over previous
//
#include <hip/hip_runtime.h>
#include <math.h>

#define B 1024
#define T 512
#define S 48
#define SOS 47

// broadcast lane l's value to all lanes via the SGPR file (VALU op)
__device__ __forceinline__ float rdlanef(float v, int l) {
    return __int_as_float(__builtin_amdgcn_readlane(__float_as_int(v), l));
}

// true broadcast of lane j's value via the DS crossbar (DS-pipe op).
// Uniform address 4*j => every lane pulls lane j; returns the exact same
// 32-bit value v_readlane would. Address constants are loop-invariant and
// get hoisted into VGPRs once.
__device__ __forceinline__ float bpermf(float v, int j) {
    return __int_as_float(__builtin_amdgcn_ds_bpermute(4 * j, __float_as_int(v)));
}

// ---------------------------------------------------------------------------
// Fused CRF loss. One wave per row; lane i owns state i; expT row in VGPRs.
// Scan kept in exp space with DELAYED normalization:
//   invariant  u_t = q * exp(M)   (exact; r_s == exp(-l_s) pending factor)
//   live step: q' = (expT q) * exp(emis - er) * r_s ;  M += er + l_s
//              then r_s = rcp(d1), l_s = log(d1)   [off critical chain]
//
// ROUND 3 (this session): q-broadcast transport moved from v_readlane (VALU)
// to ds_bpermute with UNIFORM address (DS crossbar true-broadcast).
//   - Round 1 (all-readlane, 145us): VALUBusy 60%, ~408 busy cyc/step.
//     Static count (48 rl + 48 fma + ~20 overhead) only reconciles if
//     readlane costs ~4 cyc -> ~half the VALU busy time is pure transport.
//   - Round 2 (LDS write/read pipeline, 189us, FAILED): the ds_write
//     depends on the just-selected q, anchoring the LDS round-trip to the
//     chain tail. Lesson: no write, no buffer.
//   - ds_bpermute(4*j, q) has NO write: it depends only on q (same dep the
//     readlane had), the 48 broadcasts are mutually independent, issue on
//     the DS pipe, and pipeline up to lgkmcnt depth ahead of their fmas.
//     VALU stream per step drops ~40%; DS occupancy runs concurrently.
// Transport bits are EXACTLY what readlane delivered; accumulation order
// unchanged (ax: j%4==0, ...) -> output bitwise identical to round 1.
// Emission/mask prefetch double-buffered per 8-step block so vmem waits only
// ever hit loads aged by a full block. amdgpu_waves_per_eu(1): full VGPR
// budget; occupancy is structurally 1 wave/SIMD (1024 single-wave blocks).
// ---------------------------------------------------------------------------
__global__ __launch_bounds__(64, 1)
__attribute__((amdgpu_waves_per_eu(1)))
void crf_fused(const float* __restrict__ feat,
               const int* __restrict__ states,
               const float* __restrict__ mask,
               const float* __restrict__ trans,
               float* __restrict__ out) {
    const int b = blockIdx.x;
    const int lane = threadIdx.x;
    const int elane = (lane < S) ? lane : 0;    // lanes 48-63 shadow lane 0
    const float* f_b = feat + (size_t)b * T * S;
    const float* m_b = mask + b * T;
    const int* st_b = states + b * T;

    // ---- numerator (latency overlaps expT setup) ----
    float nsum = 0.f;
#pragma unroll
    for (int k2 = 0; k2 < T / 64; ++k2) {
        const int t = lane + k2 * 64;
        const int st = st_b[t];
        const int pv = (t == 0) ? SOS : st_b[t - 1];
        nsum += (f_b[t * S + st] + trans[st * S + pv]) * m_b[t];
    }

    // ---- expT row for this lane; exp(-9999) underflows to exact 0 ----
    float expT[S];
    {
        const float4* t4 = (const float4*)(trans + elane * S);
#pragma unroll
        for (int j4 = 0; j4 < S / 4; ++j4) {
            const float4 tv = t4[j4];
            expT[4 * j4 + 0] = (lane < S) ? __expf(tv.x) : 0.f;
            expT[4 * j4 + 1] = (lane < S) ? __expf(tv.y) : 0.f;
            expT[4 * j4 + 2] = (lane < S) ? __expf(tv.z) : 0.f;
            expT[4 * j4 + 3] = (lane < S) ? __expf(tv.w) : 0.f;
        }
    }

    // ---- scan state ----
    float q = (lane == SOS) ? 1.f : 0.f;        // lanes >= 48 hold 0 forever
    float M = 0.f;
    float r_s = 1.f, l_s = 0.f;      // pending normalizer: r_s == exp(-l_s)

    // emission/mask double-buffered block rings (8 steps per block)
    float ering[2][8], mring[2][8];
#pragma unroll
    for (int k = 0; k < 8; ++k) {
        ering[0][k] = f_b[k * S + elane];
        mring[0][k] = m_b[k];
    }

#pragma unroll 2
    for (int tb = 0; tb < T / 8; ++tb) {
        const int pb = tb & 1;
        // issue next block's loads now; consumed a full block later
        const int tn = ((tb + 1) & (T / 8 - 1)) * 8;   // wrap: last refill unused
#pragma unroll
        for (int k = 0; k < 8; ++k) {
            ering[pb ^ 1][k] = f_b[(tn + k) * S + elane];
            mring[pb ^ 1][k] = m_b[tn + k];
        }
#pragma unroll
        for (int k = 0; k < 8; ++k) {
            // off-chain: per-lane factor from prefetched emission
            const float emis = ering[pb][k];
            const float er = rdlanef(emis, 1);
            const float F = __expf(emis - er) * r_s;
            // chain: DS-crossbar-broadcast dot d_i = expT[i] . q
            // (48 ds_bpermute on the DS pipe + 48 v_fmac on the VALU;
            //  bitwise-identical values and accumulation order to round 1)
            float ax = 0.f, ay = 0.f, az = 0.f, aw = 0.f;
#pragma unroll
            for (int j4 = 0; j4 < S / 4; ++j4) {
                ax = fmaf(expT[4 * j4 + 0], bpermf(q, 4 * j4 + 0), ax);
                ay = fmaf(expT[4 * j4 + 1], bpermf(q, 4 * j4 + 1), ay);
                az = fmaf(expT[4 * j4 + 2], bpermf(q, 4 * j4 + 2), az);
                aw = fmaf(expT[4 * j4 + 3], bpermf(q, 4 * j4 + 3), aw);
            }
            const float d = (ax + ay) + (az + aw);
            const float qn = d * F;
            const bool live = (mring[pb][k] != 0.f);
            q = live ? qn : q;                  // SELECT, never blend
            // off-chain: next normalizer + shift bookkeeping
            M = live ? (M + er + l_s) : M;      // uses OLD l_s, then update
            const float dr = rdlanef(d, 1);     // lane1 dot: provably > 0
            const float nl = __logf(dr);
            const float nr = __builtin_amdgcn_rcpf(dr);
            r_s = live ? nr : r_s;
            l_s = live ? nl : l_s;
        }
    }

    // ---- epilogue: denom = M + log(sum_i q_i); out = denom - numer ----
    float ps = q;                               // lanes >= 48 hold 0
#pragma unroll
    for (int off = 32; off > 0; off >>= 1) {
        ps += __shfl_xor(ps, off, 64);
        nsum += __shfl_xor(nsum, off, 64);
    }
    if (lane == 0) out[b] = M + __logf(ps) - nsum;
}

extern "C" void kernel_launch(void* const* d_in, const int* in_sizes, int n_in,
                              void* d_out, int out_size, void* d_ws, size_t ws_size,
                              hipStream_t stream) {
    const float* feat   = (const float*)d_in[0];   // (B,T,S) f32
    const int*   states = (const int*)d_in[1];     // (B,T) i32
    const float* mask   = (const float*)d_in[2];   // (B,T) f32
    const float* trans  = (const float*)d_in[3];   // (S,S) f32
    float* out = (float*)d_out;                    // (B,) f32

    crf_fused<<<dim3(B), dim3(64), 0, stream>>>(feat, states, mask, trans, out);
}